// Round 1
// baseline (725.828 us; speedup 1.0000x reference)
//
#include <hip/hip_runtime.h>
#include <math.h>

#define NFFT   1024
#define WINL   640
#define HOP    320
#define NMEL   40
#define NCEP   13
#define BATCH  1024
#define NSAMP  16000
#define NFRAME 49
#define NSPEC  513
#define PI_F   3.14159265358979323846f

// ---------------------------------------------------------------------------
// Stage 1: per (batch, frame) block — window, 1024-pt FFT (LDS, radix-2 DIT,
// precomputed twiddle table), magnitude, mel projection, log, DCT, lifter.
// Writes the 13 cepstra to their final positions in out (channels 0..12 of 39).
// ---------------------------------------------------------------------------
__global__ __launch_bounds__(256) void mfcc_stage1(
    const float* __restrict__ wave,
    const float* __restrict__ mel_fb,   // [513][40] row-major
    float* __restrict__ out)            // [B][49][39]
{
    __shared__ float re[NFFT];
    __shared__ float im[NFFT];
    __shared__ float twr[NFFT / 2];
    __shared__ float twi[NFFT / 2];
    __shared__ float logmel[NMEL];

    const int tid = threadIdx.x;
    const int b = blockIdx.x / NFRAME;
    const int f = blockIdx.x % NFRAME;
    const float* w = wave + (size_t)b * NSAMP + (size_t)f * HOP;

    // Twiddle table: tw[k] = exp(-2*pi*i*k/1024), k = 0..511
    for (int k = tid; k < NFFT / 2; k += 256) {
        float s, c;
        __sincosf(-2.0f * PI_F * (float)k / (float)NFFT, &s, &c);
        twr[k] = c;
        twi[k] = s;
    }

    // Load + Hann window, deposit at bit-reversed index (zeros beyond WINL)
    for (int i = tid; i < NFFT; i += 256) {
        float v = 0.0f;
        if (i < WINL) {
            float wn = 0.5f - 0.5f * __cosf(2.0f * PI_F * (float)i / (float)WINL);
            v = w[i] * wn;
        }
        int j = (int)(__brev((unsigned)i) >> 22);   // 10-bit reversal
        re[j] = v;
        im[j] = 0.0f;
    }
    __syncthreads();

    // Radix-2 DIT: 10 stages, 512 butterflies/stage, 2 per thread
    for (int s = 1; s <= 10; ++s) {
        const int half  = 1 << (s - 1);
        const int m     = half << 1;
        const int shift = 10 - s;
        for (int bf = tid; bf < NFFT / 2; bf += 256) {
            const int grp = bf >> (s - 1);
            const int pos = bf & (half - 1);
            const int i0  = grp * m + pos;
            const int i1  = i0 + half;
            const int tk  = pos << shift;
            const float wr = twr[tk], wi = twi[tk];
            const float xr = re[i1], xi = im[i1];
            const float tr = wr * xr - wi * xi;
            const float ti = wr * xi + wi * xr;
            const float ar = re[i0], ai = im[i0];
            re[i1] = ar - tr;  im[i1] = ai - ti;
            re[i0] = ar + tr;  im[i0] = ai + ti;
        }
        __syncthreads();
    }

    // Magnitudes, bins 0..512 (elementwise, safe to write in place)
    for (int i = tid; i <= NFFT / 2; i += 256) {
        re[i] = sqrtf(re[i] * re[i] + im[i] * im[i]);
    }
    __syncthreads();

    // Mel projection + log (row 0 of mel_fb is all-zero padding; skip bin 0)
    if (tid < NMEL) {
        float acc = 0.0f;
        for (int k = 1; k < NSPEC; ++k) {
            acc += re[k] * mel_fb[k * NMEL + tid];
        }
        logmel[tid] = __logf(acc + 1e-6f);
    }
    __syncthreads();

    // DCT-II + scale + lifter; write channels 0..12 of the 39-wide output row
    if (tid < NCEP) {
        const float c = (float)tid;
        float acc = 0.0f;
        #pragma unroll
        for (int m = 0; m < NMEL; ++m) {
            acc += logmel[m] *
                   2.0f * __cosf(PI_F * (2.0f * (float)m + 1.0f) * c / (2.0f * (float)NMEL));
        }
        const float scale = rsqrtf(2.0f * (float)NMEL);
        const float lift  = 1.0f + (22.0f * 0.5f) * __sinf(PI_F * c / 22.0f);
        out[((size_t)b * NFRAME + f) * (3 * NCEP) + tid] = acc * scale * lift;
    }
}

// ---------------------------------------------------------------------------
// Stage 2: per-batch block — read cepstra (channels 0..12) back from out,
// compute delta and delta-delta with edge replication, write channels 13..38.
// ---------------------------------------------------------------------------
__global__ __launch_bounds__(128) void mfcc_stage2(float* __restrict__ out)
{
    __shared__ float x [NFRAME * NCEP];
    __shared__ float d1[NFRAME * NCEP];

    const int b = blockIdx.x;
    const int tid = threadIdx.x;
    const int TC = NFRAME * NCEP;

    for (int i = tid; i < TC; i += 128) {
        const int t = i / NCEP, c = i - t * NCEP;
        x[i] = out[((size_t)b * NFRAME + t) * (3 * NCEP) + c];
    }
    __syncthreads();

    // d1 = delta(x): denom = 2*(1^2+2^2) = 10
    for (int i = tid; i < TC; i += 128) {
        const int t = i / NCEP, c = i - t * NCEP;
        float acc = 0.0f;
        #pragma unroll
        for (int k = -2; k <= 2; ++k) {
            if (k == 0) continue;
            int tt = t + k;
            tt = tt < 0 ? 0 : (tt > NFRAME - 1 ? NFRAME - 1 : tt);
            acc += (float)k * x[tt * NCEP + c];
        }
        d1[i] = acc * 0.1f;
    }
    __syncthreads();

    // d2 = delta(d1), and store both
    for (int i = tid; i < TC; i += 128) {
        const int t = i / NCEP, c = i - t * NCEP;
        float acc = 0.0f;
        #pragma unroll
        for (int k = -2; k <= 2; ++k) {
            if (k == 0) continue;
            int tt = t + k;
            tt = tt < 0 ? 0 : (tt > NFRAME - 1 ? NFRAME - 1 : tt);
            acc += (float)k * d1[tt * NCEP + c];
        }
        const size_t base = ((size_t)b * NFRAME + t) * (3 * NCEP);
        out[base +     NCEP + c] = d1[i];
        out[base + 2 * NCEP + c] = acc * 0.1f;
    }
}

extern "C" void kernel_launch(void* const* d_in, const int* in_sizes, int n_in,
                              void* d_out, int out_size, void* d_ws, size_t ws_size,
                              hipStream_t stream)
{
    const float* wave   = (const float*)d_in[0];   // [1024][16000] f32
    const float* mel_fb = (const float*)d_in[1];   // [513][40] f32
    float* out = (float*)d_out;                    // [1024][49][39][1] f32

    mfcc_stage1<<<BATCH * NFRAME, 256, 0, stream>>>(wave, mel_fb, out);
    mfcc_stage2<<<BATCH, 128, 0, stream>>>(out);
}

// Round 2
// 246.558 us; speedup vs baseline: 2.9438x; 2.9438x over previous
//
#include <hip/hip_runtime.h>
#include <math.h>

#define NMEL   40
#define NCEP   13
#define BATCH  1024
#define NSAMP  16000
#define NFRAME 49
#define PI_F   3.14159265358979323846f

// d_ws float layout
#define WS_WIN  0        // 640 floats: Hann window
#define WS_R    640      // 512 float2: W_1024^k, k=0..511 (1024 floats)
#define WS_DT   1664     // 520 floats: DCT * 1/sqrt(80) * lifter, [40][13]
#define WS_WT   2184     // 40*68 floats: sparse mel weights
#define WS_LO   4904     // 40 ints: first nonzero bin per mel
#define WS_WID  4944     // 40 ints: nonzero width per mel
#define WS_TOT  4984

// radix-2 DIF butterfly on register arrays
#define BFLY(i0, i1, wr, wi) {                        \
    float tr = zr[i0] - zr[i1], ti = zi[i0] - zi[i1]; \
    zr[i0] += zr[i1]; zi[i0] += zi[i1];               \
    zr[i1] = tr*(wr) - ti*(wi);                       \
    zi[i1] = tr*(wi) + ti*(wr); }

// ---------------------------------------------------------------------------
// Prep: build window / twiddle / DCT / sparse-mel tables in d_ws (every call).
// ---------------------------------------------------------------------------
__global__ __launch_bounds__(256) void mfcc_prep(
    const float* __restrict__ mel_fb, float* __restrict__ ws)
{
    const int tid = threadIdx.x;
    for (int i = tid; i < 640; i += 256)
        ws[WS_WIN + i] = 0.5f - 0.5f * cosf(2.0f * PI_F * (float)i / 640.0f);

    float2* R = (float2*)(ws + WS_R);
    for (int k = tid; k < 512; k += 256) {
        float s, c;
        sincosf(-2.0f * PI_F * (float)k / 1024.0f, &s, &c);
        R[k] = make_float2(c, s);
    }

    for (int i = tid; i < 520; i += 256) {
        int m = i / 13, c = i - m * 13;
        float d    = 2.0f * cosf(PI_F * (2.0f * m + 1.0f) * (float)c / 80.0f);
        float lift = 1.0f + 11.0f * sinf(PI_F * (float)c / 22.0f);
        ws[WS_DT + i] = d * 0.11180339887498949f * lift;  // 1/sqrt(80)
    }

    // sparse mel: each filter's support is contiguous
    if (tid < NMEL) {
        int lo = -1, hi = -1;
        for (int k = 0; k < 513; ++k) {
            float w = mel_fb[k * NMEL + tid];
            if (w > 0.0f) { if (lo < 0) lo = k; hi = k; }
        }
        int wid = (lo < 0) ? 0 : hi - lo + 1;
        if (wid > 68) wid = 68;
        if (lo < 0) lo = 0;
        ((int*)ws)[WS_LO  + tid] = lo;
        ((int*)ws)[WS_WID + tid] = wid;
        for (int i = 0; i < wid; ++i)
            ws[WS_WT + tid * 68 + i] = mel_fb[(lo + i) * NMEL + tid];
    }
}

// ---------------------------------------------------------------------------
// Stage 1: one wave per frame (4 frames/block). 512-pt complex FFT of packed
// real samples (8 pts/lane in registers, 9 DIF stages in 3 register groups,
// 2 LDS exchanges), real-split, |X|, sparse mel, log, DCT+lifter.
// ---------------------------------------------------------------------------
__global__ __launch_bounds__(256) void mfcc_stage1(
    const float* __restrict__ wave, const float* __restrict__ ws,
    float* __restrict__ out)
{
    __shared__ float2 Zs[4][580];
    __shared__ float  mags[4][516];
    __shared__ float  lms[4][40];

    const int tid = threadIdx.x;
    const int wv  = tid >> 6;
    const int L   = tid & 63;
    const int s   = L & 7;
    const int frame = blockIdx.x * 4 + wv;          // grid*4 == 50176 exactly
    const int b = frame / NFRAME;
    const int f = frame - b * NFRAME;

    float2* Z  = Zs[wv];
    float* mag = mags[wv];
    float* lm  = lms[wv];
    const float2* R   = (const float2*)(ws + WS_R);
    const float2* win = (const float2*)(ws + WS_WIN);
    const float2* xin = (const float2*)(wave + (size_t)b * NSAMP + (size_t)f * 320);

    float zr[8], zi[8];
    #pragma unroll
    for (int j = 0; j < 8; ++j) { zr[j] = 0.0f; zi[j] = 0.0f; }
    // z[n] = x[2n]*w[2n] + i*x[2n+1]*w[2n+1], n = L + 64j (nonzero only j<5)
    #pragma unroll
    for (int j = 0; j < 5; ++j) {
        int n = L + 64 * j;
        float2 x = xin[n];
        float2 w = win[n];
        zr[j] = x.x * w.x;
        zi[j] = x.y * w.y;
    }

    // ---- register stages on coset n = L + 64j ----
    // Stage A: size 512, pairs (j, j+4), tw W_512^(L+64j) = R[2(L+64j)]
    #pragma unroll
    for (int j = 0; j < 4; ++j) {
        float2 w = R[2 * (L + 64 * j)];
        BFLY(j, j + 4, w.x, w.y);
    }
    // Stage B: size 256, pairs (i0, i0+2), tw W_256^(L+64(i0&1)) = R[4(...)]
    #pragma unroll
    for (int g = 0; g < 8; g += 4) {
        #pragma unroll
        for (int j = 0; j < 2; ++j) {
            float2 w = R[4 * (L + 64 * j)];
            BFLY(g + j, g + j + 2, w.x, w.y);
        }
    }
    // Stage C: size 128, pairs (i0, i0+1), tw W_128^L = R[8L]
    {
        float2 w = R[8 * L];
        #pragma unroll
        for (int i0 = 0; i0 < 8; i0 += 2) BFLY(i0, i0 + 1, w.x, w.y);
    }

    // ---- exchange 1: n = L+64j  ->  n = 64*(L>>3) + 8j + s ----
    #pragma unroll
    for (int j = 0; j < 8; ++j) {
        int n = L + 64 * j;
        Z[n + (n >> 3)] = make_float2(zr[j], zi[j]);
    }
    __syncthreads();
    #pragma unroll
    for (int j = 0; j < 8; ++j) {
        int n = (L >> 3) * 64 + 8 * j + s;
        float2 v = Z[n + (n >> 3)];
        zr[j] = v.x; zi[j] = v.y;
    }

    // ---- register stages on coset q = 8j + s within 64-blocks ----
    // Stage D: size 64, pairs (j, j+4), tw W_64^(8j+s) = R[128j+16s]
    #pragma unroll
    for (int j = 0; j < 4; ++j) {
        float2 w = R[128 * j + 16 * s];
        BFLY(j, j + 4, w.x, w.y);
    }
    // Stage E: size 32, pairs (i0, i0+2), tw W_32^(8(i0&1)+s) = R[256j+32s]
    #pragma unroll
    for (int g = 0; g < 8; g += 4) {
        #pragma unroll
        for (int j = 0; j < 2; ++j) {
            float2 w = R[256 * j + 32 * s];
            BFLY(g + j, g + j + 2, w.x, w.y);
        }
    }
    // Stage F: size 16, pairs (i0, i0+1), tw W_16^s = R[64s]
    {
        float2 w = R[64 * s];
        #pragma unroll
        for (int i0 = 0; i0 < 8; i0 += 2) BFLY(i0, i0 + 1, w.x, w.y);
    }

    // ---- exchange 2: -> contiguous n = 8L + j ----
    #pragma unroll
    for (int j = 0; j < 8; ++j) {
        int n = (L >> 3) * 64 + 8 * j + s;
        Z[n + (n >> 6)] = make_float2(zr[j], zi[j]);
    }
    __syncthreads();
    {
        int base = 8 * L + (L >> 3);
        #pragma unroll
        for (int j = 0; j < 8; ++j) {
            float2 v = Z[base + j];
            zr[j] = v.x; zi[j] = v.y;
        }
    }

    // ---- register stages on q = j (size 8,4,2) ----
    {
        const float C = 0.70710678118654752f;
        const float w8r[4] = { 1.0f,  C, 0.0f, -C };
        const float w8i[4] = { 0.0f, -C, -1.0f, -C };
        #pragma unroll
        for (int j = 0; j < 4; ++j) BFLY(j, j + 4, w8r[j], w8i[j]);
        #pragma unroll
        for (int g = 0; g < 8; g += 4) {
            BFLY(g + 0, g + 2, 1.0f, 0.0f);
            BFLY(g + 1, g + 3, 0.0f, -1.0f);
        }
        #pragma unroll
        for (int i0 = 0; i0 < 8; i0 += 2) BFLY(i0, i0 + 1, 1.0f, 0.0f);
    }

    // ---- write Z[k] at true k = rev3(j)*64 + rev6(L), padded by (k>>6) ----
    {
        const int rev3t[8] = { 0, 4, 2, 6, 1, 5, 3, 7 };
        int r6 = (int)(__brev((unsigned)L) >> 26);
        #pragma unroll
        for (int j = 0; j < 8; ++j) {
            int k = rev3t[j] * 64 + r6;
            Z[k + rev3t[j]] = make_float2(zr[j], zi[j]);
        }
    }
    __syncthreads();

    // ---- real-split + magnitude: X[k] = Xe[k] + W_1024^k * Xo[k] ----
    #pragma unroll
    for (int j = 0; j < 8; ++j) {
        int k = L + 64 * j;
        if (k == 0) {
            float2 z0 = Z[0];
            mag[0]   = fabsf(z0.x + z0.y);
            mag[512] = fabsf(z0.x - z0.y);
        } else {
            int n2 = 512 - k;
            float2 A = Z[k  + (k  >> 6)];
            float2 B = Z[n2 + (n2 >> 6)];
            float xer = 0.5f * (A.x + B.x), xei = 0.5f * (A.y - B.y);
            float xor_ = 0.5f * (A.y + B.y), xoi = -0.5f * (A.x - B.x);
            float2 w = R[k];
            float xr = xer + w.x * xor_ - w.y * xoi;
            float xi = xei + w.x * xoi + w.y * xor_;
            mag[k] = sqrtf(xr * xr + xi * xi);
        }
    }
    __syncthreads();

    // ---- sparse mel + log ----
    if (L < NMEL) {
        int lo  = ((const int*)ws)[WS_LO  + L];
        int wid = ((const int*)ws)[WS_WID + L];
        const float* wt = ws + WS_WT + L * 68;
        float acc = 0.0f;
        for (int i = 0; i < wid; ++i) acc += mag[lo + i] * wt[i];
        lm[L] = __logf(acc + 1e-6f);
    }
    __syncthreads();

    // ---- DCT + scale + lifter (folded into WS_DT) ----
    if (L < NCEP) {
        float acc = 0.0f;
        #pragma unroll
        for (int m = 0; m < NMEL; ++m)
            acc += lm[m] * ws[WS_DT + m * 13 + L];
        out[(size_t)frame * (3 * NCEP) + L] = acc;
    }
}

// ---------------------------------------------------------------------------
// Stage 2: per-batch deltas (unchanged from round 1).
// ---------------------------------------------------------------------------
__global__ __launch_bounds__(128) void mfcc_stage2(float* __restrict__ out)
{
    __shared__ float x [NFRAME * NCEP];
    __shared__ float d1[NFRAME * NCEP];

    const int b = blockIdx.x;
    const int tid = threadIdx.x;
    const int TC = NFRAME * NCEP;

    for (int i = tid; i < TC; i += 128) {
        const int t = i / NCEP, c = i - t * NCEP;
        x[i] = out[((size_t)b * NFRAME + t) * (3 * NCEP) + c];
    }
    __syncthreads();

    for (int i = tid; i < TC; i += 128) {
        const int t = i / NCEP, c = i - t * NCEP;
        float acc = 0.0f;
        #pragma unroll
        for (int k = -2; k <= 2; ++k) {
            if (k == 0) continue;
            int tt = t + k;
            tt = tt < 0 ? 0 : (tt > NFRAME - 1 ? NFRAME - 1 : tt);
            acc += (float)k * x[tt * NCEP + c];
        }
        d1[i] = acc * 0.1f;
    }
    __syncthreads();

    for (int i = tid; i < TC; i += 128) {
        const int t = i / NCEP, c = i - t * NCEP;
        float acc = 0.0f;
        #pragma unroll
        for (int k = -2; k <= 2; ++k) {
            if (k == 0) continue;
            int tt = t + k;
            tt = tt < 0 ? 0 : (tt > NFRAME - 1 ? NFRAME - 1 : tt);
            acc += (float)k * d1[tt * NCEP + c];
        }
        const size_t base = ((size_t)b * NFRAME + t) * (3 * NCEP);
        out[base +     NCEP + c] = d1[i];
        out[base + 2 * NCEP + c] = acc * 0.1f;
    }
}

extern "C" void kernel_launch(void* const* d_in, const int* in_sizes, int n_in,
                              void* d_out, int out_size, void* d_ws, size_t ws_size,
                              hipStream_t stream)
{
    const float* wave   = (const float*)d_in[0];   // [1024][16000] f32
    const float* mel_fb = (const float*)d_in[1];   // [513][40] f32
    float* out = (float*)d_out;                    // [1024][49][39][1] f32
    float* ws  = (float*)d_ws;

    mfcc_prep<<<1, 256, 0, stream>>>(mel_fb, ws);
    mfcc_stage1<<<(BATCH * NFRAME) / 4, 256, 0, stream>>>(wave, ws, out);
    mfcc_stage2<<<BATCH, 128, 0, stream>>>(out);
}

// Round 3
// 218.571 us; speedup vs baseline: 3.3208x; 1.1280x over previous
//
#include <hip/hip_runtime.h>
#include <math.h>

#define NMEL   40
#define NCEP   13
#define BATCH  1024
#define NSAMP  16000
#define NFRAME 49
#define PI_F   3.14159265358979323846f

// d_ws float layout
#define WS_WIN  0        // 640 floats: Hann window
#define WS_R    640      // 512 float2: W_1024^k, k=0..511 (1024 floats)
#define WS_DT   1664     // 520 floats: DCT * 1/sqrt(80) * lifter, [40][13]
#define WS_WT   2184     // 40*68 floats: sparse mel weights
#define WS_LO   4904     // 40 ints: first nonzero bin per mel
#define WS_WID  4944     // 40 ints: nonzero width per mel
#define WS_TOT  4984

// radix-2 DIF butterfly on register arrays
#define BFLY(i0, i1, wr, wi) {                        \
    float tr = zr[i0] - zr[i1], ti = zi[i0] - zi[i1]; \
    zr[i0] += zr[i1]; zi[i0] += zi[i1];               \
    zr[i1] = tr*(wr) - ti*(wi);                       \
    zi[i1] = tr*(wi) + ti*(wr); }

// ---------------------------------------------------------------------------
// Prep (parallel): blocks 0..39 = one wave per mel filter; blocks 40..47 =
// window / twiddle / DCT tables, grid-stride.
// ---------------------------------------------------------------------------
__global__ __launch_bounds__(64) void mfcc_prep(
    const float* __restrict__ mel_fb, float* __restrict__ ws)
{
    const int blk = blockIdx.x;
    const int L   = threadIdx.x;

    if (blk < NMEL) {
        const int m = blk;
        int lo = 1 << 20, hi = -1;
        for (int k = L; k < 513; k += 64) {
            float w = mel_fb[k * NMEL + m];
            if (w > 0.0f) { lo = min(lo, k); hi = max(hi, k); }
        }
        for (int off = 32; off; off >>= 1) {
            lo = min(lo, __shfl_down(lo, off));
            hi = max(hi, __shfl_down(hi, off));
        }
        lo = __shfl(lo, 0); hi = __shfl(hi, 0);
        int wid = (hi < 0) ? 0 : hi - lo + 1;
        if (hi < 0) lo = 0;
        if (wid > 68) wid = 68;
        if (L == 0) {
            ((int*)ws)[WS_LO  + m] = lo;
            ((int*)ws)[WS_WID + m] = wid;
        }
        for (int i = L; i < wid; i += 64)
            ws[WS_WT + m * 68 + i] = mel_fb[(lo + i) * NMEL + m];
    } else {
        const int idx = (blk - NMEL) * 64 + L;      // 512 lanes over 1672 items
        for (int i = idx; i < 640 + 512 + 520; i += 512) {
            if (i < 640) {
                ws[WS_WIN + i] = 0.5f - 0.5f * cosf(2.0f * PI_F * (float)i / 640.0f);
            } else if (i < 1152) {
                int k = i - 640;
                float s, c;
                sincosf(-2.0f * PI_F * (float)k / 1024.0f, &s, &c);
                ((float2*)(ws + WS_R))[k] = make_float2(c, s);
            } else {
                int j = i - 1152;
                int m = j / 13, c0 = j - m * 13;
                float d    = 2.0f * cosf(PI_F * (2.0f * m + 1.0f) * (float)c0 / 80.0f);
                float lift = 1.0f + 11.0f * sinf(PI_F * (float)c0 / 22.0f);
                ws[WS_DT + j] = d * 0.11180339887498949f * lift;   // 1/sqrt(80)
            }
        }
    }
}

// ---------------------------------------------------------------------------
// Stage 1: one wave per frame (4 frames/block). 512-pt complex FFT of packed
// real samples (8 pts/lane in registers, 2 LDS exchanges), real-split, |X|
// (registers, then overlaid onto the dead FFT buffer to save LDS), sparse
// mel, log, DCT+lifter.  LDS/block = 19.2 KB -> 8 blocks/CU.
// ---------------------------------------------------------------------------
__global__ __launch_bounds__(256) void mfcc_stage1(
    const float* __restrict__ wave, const float* __restrict__ ws,
    float* __restrict__ out)
{
    __shared__ float2 Zs[4][580];
    __shared__ float  lms[4][40];

    const int tid = threadIdx.x;
    const int wv  = tid >> 6;
    const int L   = tid & 63;
    const int s   = L & 7;
    const int frame = blockIdx.x * 4 + wv;          // grid*4 == 50176 exactly
    const int b = frame / NFRAME;
    const int f = frame - b * NFRAME;

    float2* Z  = Zs[wv];
    float* mag = (float*)Zs[wv];                    // overlay: valid after FFT dies
    float* lm  = lms[wv];
    const float2* R   = (const float2*)(ws + WS_R);
    const float2* win = (const float2*)(ws + WS_WIN);
    const float2* xin = (const float2*)(wave + (size_t)b * NSAMP + (size_t)f * 320);

    float zr[8], zi[8];
    #pragma unroll
    for (int j = 0; j < 8; ++j) { zr[j] = 0.0f; zi[j] = 0.0f; }
    // z[n] = x[2n]*w[2n] + i*x[2n+1]*w[2n+1], n = L + 64j (nonzero only j<5)
    #pragma unroll
    for (int j = 0; j < 5; ++j) {
        int n = L + 64 * j;
        float2 x = xin[n];
        float2 w = win[n];
        zr[j] = x.x * w.x;
        zi[j] = x.y * w.y;
    }

    // ---- register stages on coset n = L + 64j ----
    #pragma unroll
    for (int j = 0; j < 4; ++j) {                   // size 512
        float2 w = R[2 * (L + 64 * j)];
        BFLY(j, j + 4, w.x, w.y);
    }
    #pragma unroll
    for (int g = 0; g < 8; g += 4) {                // size 256
        #pragma unroll
        for (int j = 0; j < 2; ++j) {
            float2 w = R[4 * (L + 64 * j)];
            BFLY(g + j, g + j + 2, w.x, w.y);
        }
    }
    {                                               // size 128
        float2 w = R[8 * L];
        #pragma unroll
        for (int i0 = 0; i0 < 8; i0 += 2) BFLY(i0, i0 + 1, w.x, w.y);
    }

    // ---- exchange 1: n = L+64j  ->  n = 64*(L>>3) + 8j + s ----
    #pragma unroll
    for (int j = 0; j < 8; ++j) {
        int n = L + 64 * j;
        Z[n + (n >> 3)] = make_float2(zr[j], zi[j]);
    }
    __syncthreads();
    #pragma unroll
    for (int j = 0; j < 8; ++j) {
        int n = (L >> 3) * 64 + 8 * j + s;
        float2 v = Z[n + (n >> 3)];
        zr[j] = v.x; zi[j] = v.y;
    }

    // ---- register stages on coset q = 8j + s within 64-blocks ----
    #pragma unroll
    for (int j = 0; j < 4; ++j) {                   // size 64
        float2 w = R[128 * j + 16 * s];
        BFLY(j, j + 4, w.x, w.y);
    }
    #pragma unroll
    for (int g = 0; g < 8; g += 4) {                // size 32
        #pragma unroll
        for (int j = 0; j < 2; ++j) {
            float2 w = R[256 * j + 32 * s];
            BFLY(g + j, g + j + 2, w.x, w.y);
        }
    }
    {                                               // size 16
        float2 w = R[64 * s];
        #pragma unroll
        for (int i0 = 0; i0 < 8; i0 += 2) BFLY(i0, i0 + 1, w.x, w.y);
    }

    // ---- exchange 2: -> contiguous n = 8L + j ----
    __syncthreads();                                // protect buffer reuse
    #pragma unroll
    for (int j = 0; j < 8; ++j) {
        int n = (L >> 3) * 64 + 8 * j + s;
        Z[n + (n >> 6)] = make_float2(zr[j], zi[j]);
    }
    __syncthreads();
    {
        int base = 8 * L + (L >> 3);
        #pragma unroll
        for (int j = 0; j < 8; ++j) {
            float2 v = Z[base + j];
            zr[j] = v.x; zi[j] = v.y;
        }
    }

    // ---- register stages on q = j (size 8,4,2) ----
    {
        const float C = 0.70710678118654752f;
        const float w8r[4] = { 1.0f,  C, 0.0f, -C };
        const float w8i[4] = { 0.0f, -C, -1.0f, -C };
        #pragma unroll
        for (int j = 0; j < 4; ++j) BFLY(j, j + 4, w8r[j], w8i[j]);
        #pragma unroll
        for (int g = 0; g < 8; g += 4) {
            BFLY(g + 0, g + 2, 1.0f, 0.0f);
            BFLY(g + 1, g + 3, 0.0f, -1.0f);
        }
        #pragma unroll
        for (int i0 = 0; i0 < 8; i0 += 2) BFLY(i0, i0 + 1, 1.0f, 0.0f);
    }

    // ---- write Z[k] at true k = rev3(j)*64 + rev6(L), padded by (k>>6) ----
    __syncthreads();                                // protect buffer reuse
    {
        const int rev3t[8] = { 0, 4, 2, 6, 1, 5, 3, 7 };
        int r6 = (int)(__brev((unsigned)L) >> 26);
        #pragma unroll
        for (int j = 0; j < 8; ++j) {
            int k = rev3t[j] * 64 + r6;
            Z[k + rev3t[j]] = make_float2(zr[j], zi[j]);
        }
    }
    __syncthreads();

    // ---- real-split + magnitude into registers ----
    float mg[8], m512 = 0.0f;
    #pragma unroll
    for (int j = 0; j < 8; ++j) {
        int k = L + 64 * j;
        if (k == 0) {
            float2 z0 = Z[0];
            mg[j] = fabsf(z0.x + z0.y);
            m512  = fabsf(z0.x - z0.y);
        } else {
            int n2 = 512 - k;
            float2 A  = Z[k  + (k  >> 6)];
            float2 Bv = Z[n2 + (n2 >> 6)];
            float xer = 0.5f * (A.x + Bv.x), xei = 0.5f * (A.y - Bv.y);
            float xor_ = 0.5f * (A.y + Bv.y), xoi = -0.5f * (A.x - Bv.x);
            float2 w = R[k];
            float xr = xer + w.x * xor_ - w.y * xoi;
            float xi = xei + w.x * xoi + w.y * xor_;
            mg[j] = sqrtf(xr * xr + xi * xi);
        }
    }
    __syncthreads();                // all Z reads done before mag overlay write
    #pragma unroll
    for (int j = 0; j < 8; ++j) mag[L + 64 * j] = mg[j];
    if (L == 0) mag[512] = m512;
    __syncthreads();

    // ---- sparse mel + log ----
    if (L < NMEL) {
        int lo  = ((const int*)ws)[WS_LO  + L];
        int wid = ((const int*)ws)[WS_WID + L];
        const float* wt = ws + WS_WT + L * 68;
        float acc = 0.0f;
        for (int i = 0; i < wid; ++i) acc += mag[lo + i] * wt[i];
        lm[L] = __logf(acc + 1e-6f);
    }
    __syncthreads();

    // ---- DCT + scale + lifter (folded into WS_DT) ----
    if (L < NCEP) {
        float acc = 0.0f;
        #pragma unroll
        for (int m = 0; m < NMEL; ++m)
            acc += lm[m] * ws[WS_DT + m * 13 + L];
        out[(size_t)frame * (3 * NCEP) + L] = acc;
    }
}

// ---------------------------------------------------------------------------
// Stage 2: per-batch deltas.
// ---------------------------------------------------------------------------
__global__ __launch_bounds__(128) void mfcc_stage2(float* __restrict__ out)
{
    __shared__ float x [NFRAME * NCEP];
    __shared__ float d1[NFRAME * NCEP];

    const int b = blockIdx.x;
    const int tid = threadIdx.x;
    const int TC = NFRAME * NCEP;

    for (int i = tid; i < TC; i += 128) {
        const int t = i / NCEP, c = i - t * NCEP;
        x[i] = out[((size_t)b * NFRAME + t) * (3 * NCEP) + c];
    }
    __syncthreads();

    for (int i = tid; i < TC; i += 128) {
        const int t = i / NCEP, c = i - t * NCEP;
        float acc = 0.0f;
        #pragma unroll
        for (int k = -2; k <= 2; ++k) {
            if (k == 0) continue;
            int tt = t + k;
            tt = tt < 0 ? 0 : (tt > NFRAME - 1 ? NFRAME - 1 : tt);
            acc += (float)k * x[tt * NCEP + c];
        }
        d1[i] = acc * 0.1f;
    }
    __syncthreads();

    for (int i = tid; i < TC; i += 128) {
        const int t = i / NCEP, c = i - t * NCEP;
        float acc = 0.0f;
        #pragma unroll
        for (int k = -2; k <= 2; ++k) {
            if (k == 0) continue;
            int tt = t + k;
            tt = tt < 0 ? 0 : (tt > NFRAME - 1 ? NFRAME - 1 : tt);
            acc += (float)k * d1[tt * NCEP + c];
        }
        const size_t base = ((size_t)b * NFRAME + t) * (3 * NCEP);
        out[base +     NCEP + c] = d1[i];
        out[base + 2 * NCEP + c] = acc * 0.1f;
    }
}

extern "C" void kernel_launch(void* const* d_in, const int* in_sizes, int n_in,
                              void* d_out, int out_size, void* d_ws, size_t ws_size,
                              hipStream_t stream)
{
    const float* wave   = (const float*)d_in[0];   // [1024][16000] f32
    const float* mel_fb = (const float*)d_in[1];   // [513][40] f32
    float* out = (float*)d_out;                    // [1024][49][39][1] f32
    float* ws  = (float*)d_ws;

    mfcc_prep<<<48, 64, 0, stream>>>(mel_fb, ws);
    mfcc_stage1<<<(BATCH * NFRAME) / 4, 256, 0, stream>>>(wave, ws, out);
    mfcc_stage2<<<BATCH, 128, 0, stream>>>(out);
}

// Round 5
// 199.549 us; speedup vs baseline: 3.6373x; 1.0953x over previous
//
#include <hip/hip_runtime.h>
#include <math.h>

#define NMEL   40
#define NCEP   13
#define BATCH  1024
#define NSAMP  16000
#define NFRAME 49
#define PI_F   3.14159265358979323846f

// d_ws float layout
#define WS_WIN  0        // 640 floats: Hann window
#define WS_R    640      // 512 float2: W_1024^k, k=0..511 (1024 floats)
#define WS_DT   1664     // 520 floats: DCT * 1/sqrt(80) * lifter, [40][13]
#define WS_BT   2184     // f16 area: Bt[48][544] mel weights transposed (13056 floats)
#define WS_TOT  15240

typedef _Float16 half8 __attribute__((ext_vector_type(8)));
typedef __fp16   fp16x2 __attribute__((ext_vector_type(2)));
typedef float f32x4 __attribute__((ext_vector_type(4)));

// wave-local LDS fence (buffers are wave-private; no block barrier needed)
#define WAVE_SYNC() asm volatile("s_waitcnt lgkmcnt(0)" ::: "memory")

// radix-2 DIF butterfly on register arrays
#define BFLY(i0, i1, wr, wi) {                        \
    float tr = zr[i0] - zr[i1], ti = zi[i0] - zi[i1]; \
    zr[i0] += zr[i1]; zi[i0] += zi[i1];               \
    zr[i1] = tr*(wr) - ti*(wi);                       \
    zi[i1] = tr*(wi) + ti*(wr); }

__device__ __forceinline__ unsigned pk_f16(float a, float b) {
    fp16x2 h = __builtin_amdgcn_cvt_pkrtz(a, b);
    union { fp16x2 h; unsigned u; } cvt; cvt.h = h;
    return cvt.u;
}

// ---------------------------------------------------------------------------
// Prep: window / twiddle / DCT tables + transposed, padded f16 mel weights.
// Bt[n][k] (n<48 rows of 544) = mel_fb[k*40+n] for n<40 && k<513, else 0.
// ---------------------------------------------------------------------------
__global__ __launch_bounds__(256) void mfcc_prep(
    const float* __restrict__ mel_fb, float* __restrict__ ws)
{
    const int idx = blockIdx.x * 256 + threadIdx.x;   // grid = 64 blocks

    _Float16* bt = (_Float16*)(ws + WS_BT);
    for (int i = idx; i < 48 * 544; i += 64 * 256) {
        int n = i / 544, k = i - n * 544;
        float v = (n < NMEL && k < 513) ? mel_fb[k * NMEL + n] : 0.0f;
        bt[i] = (_Float16)v;
    }

    if (idx < 640 + 512 + 520) {
        int i = idx;
        if (i < 640) {
            ws[WS_WIN + i] = 0.5f - 0.5f * cosf(2.0f * PI_F * (float)i / 640.0f);
        } else if (i < 1152) {
            int k = i - 640;
            float s, c;
            sincosf(-2.0f * PI_F * (float)k / 1024.0f, &s, &c);
            ((float2*)(ws + WS_R))[k] = make_float2(c, s);
        } else {
            int j = i - 1152;
            int m = j / 13, c0 = j - m * 13;
            float d    = 2.0f * cosf(PI_F * (2.0f * m + 1.0f) * (float)c0 / 80.0f);
            float lift = 1.0f + 11.0f * sinf(PI_F * (float)c0 / 22.0f);
            ws[WS_DT + j] = d * 0.11180339887498949f * lift;   // 1/sqrt(80)
        }
    }
}

// ---------------------------------------------------------------------------
// Stage 1: 16 frames per block (4 waves x 4 sequential FFTs). Per frame:
// 512-pt complex FFT of packed real samples (8 pts/lane in registers, 2
// wave-local LDS exchanges), real-split -> |X| packed f16 in registers.
// Then all mags -> LDS tile [16][552] f16 (overlaid on dead FFT buffers),
// mel projection via mfma_f32_16x16x32_f16 (3 N-tiles, waves 0..2), log,
// fp32 scalar DCT (208 threads), write 13 cepstra per frame.
// ---------------------------------------------------------------------------
__global__ __launch_bounds__(256) void mfcc_stage1(
    const float* __restrict__ wave, const float* __restrict__ ws,
    float* __restrict__ out)
{
    // LDS: union { float2 Z[4][580] } overlaid by { f16 mag[16][552] }, + lm
    __shared__ __align__(16) char smem[4 * 580 * 8 + 16 * 40 * 4];
    char* smemc = smem;
    float* lm = (float*)(smem + 4 * 580 * 8);        // [16][40] f32

    const int tid = threadIdx.x;
    const int wv  = tid >> 6;
    const int L   = tid & 63;
    const int s   = L & 7;

    float2* Z = (float2*)smem + wv * 580;            // wave-private FFT buffer
    const float2* R   = (const float2*)(ws + WS_R);
    const float2* win = (const float2*)(ws + WS_WIN);

    uint4 mgp[4];          // per-frame packed f16 magnitudes (8 per lane)
    float m512v[4] = {0.0f, 0.0f, 0.0f, 0.0f};

    #pragma unroll
    for (int fi = 0; fi < 4; ++fi) {
        const int frame = blockIdx.x * 16 + wv * 4 + fi;
        const int b = frame / NFRAME;
        const int f = frame - b * NFRAME;
        const float2* xin = (const float2*)(wave + (size_t)b * NSAMP + (size_t)f * 320);

        float zr[8], zi[8];
        #pragma unroll
        for (int j = 0; j < 8; ++j) { zr[j] = 0.0f; zi[j] = 0.0f; }
        // z[n] = x[2n]*w[2n] + i*x[2n+1]*w[2n+1], n = L + 64j (nonzero j<5)
        #pragma unroll
        for (int j = 0; j < 5; ++j) {
            int n = L + 64 * j;
            float2 x = xin[n];
            float2 w = win[n];
            zr[j] = x.x * w.x;
            zi[j] = x.y * w.y;
        }

        // ---- register stages on coset n = L + 64j ----
        #pragma unroll
        for (int j = 0; j < 4; ++j) {                   // size 512
            float2 w = R[2 * (L + 64 * j)];
            BFLY(j, j + 4, w.x, w.y);
        }
        #pragma unroll
        for (int g = 0; g < 8; g += 4) {                // size 256
            #pragma unroll
            for (int j = 0; j < 2; ++j) {
                float2 w = R[4 * (L + 64 * j)];
                BFLY(g + j, g + j + 2, w.x, w.y);
            }
        }
        {                                               // size 128
            float2 w = R[8 * L];
            #pragma unroll
            for (int i0 = 0; i0 < 8; i0 += 2) BFLY(i0, i0 + 1, w.x, w.y);
        }

        // ---- exchange 1: n = L+64j -> n = 64*(L>>3) + 8j + s ----
        WAVE_SYNC();
        #pragma unroll
        for (int j = 0; j < 8; ++j) {
            int n = L + 64 * j;
            Z[n + (n >> 3)] = make_float2(zr[j], zi[j]);
        }
        WAVE_SYNC();
        #pragma unroll
        for (int j = 0; j < 8; ++j) {
            int n = (L >> 3) * 64 + 8 * j + s;
            float2 v = Z[n + (n >> 3)];
            zr[j] = v.x; zi[j] = v.y;
        }

        // ---- register stages on coset q = 8j + s within 64-blocks ----
        #pragma unroll
        for (int j = 0; j < 4; ++j) {                   // size 64
            float2 w = R[128 * j + 16 * s];
            BFLY(j, j + 4, w.x, w.y);
        }
        #pragma unroll
        for (int g = 0; g < 8; g += 4) {                // size 32
            #pragma unroll
            for (int j = 0; j < 2; ++j) {
                float2 w = R[256 * j + 32 * s];
                BFLY(g + j, g + j + 2, w.x, w.y);
            }
        }
        {                                               // size 16
            float2 w = R[64 * s];
            #pragma unroll
            for (int i0 = 0; i0 < 8; i0 += 2) BFLY(i0, i0 + 1, w.x, w.y);
        }

        // ---- exchange 2: -> contiguous n = 8L + j ----
        WAVE_SYNC();
        #pragma unroll
        for (int j = 0; j < 8; ++j) {
            int n = (L >> 3) * 64 + 8 * j + s;
            Z[n + (n >> 6)] = make_float2(zr[j], zi[j]);
        }
        WAVE_SYNC();
        {
            int base = 8 * L + (L >> 3);
            #pragma unroll
            for (int j = 0; j < 8; ++j) {
                float2 v = Z[base + j];
                zr[j] = v.x; zi[j] = v.y;
            }
        }

        // ---- register stages on q = j (size 8,4,2) ----
        {
            const float C = 0.70710678118654752f;
            const float w8r[4] = { 1.0f,  C, 0.0f, -C };
            const float w8i[4] = { 0.0f, -C, -1.0f, -C };
            #pragma unroll
            for (int j = 0; j < 4; ++j) BFLY(j, j + 4, w8r[j], w8i[j]);
            #pragma unroll
            for (int g = 0; g < 8; g += 4) {
                BFLY(g + 0, g + 2, 1.0f, 0.0f);
                BFLY(g + 1, g + 3, 0.0f, -1.0f);
            }
            #pragma unroll
            for (int i0 = 0; i0 < 8; i0 += 2) BFLY(i0, i0 + 1, 1.0f, 0.0f);
        }

        // ---- write Z[k] at true k = rev3(j)*64 + rev6(L), pad (k>>6) ----
        WAVE_SYNC();
        {
            const int rev3t[8] = { 0, 4, 2, 6, 1, 5, 3, 7 };
            int r6 = (int)(__brev((unsigned)L) >> 26);
            #pragma unroll
            for (int j = 0; j < 8; ++j) {
                int k = rev3t[j] * 64 + r6;
                Z[k + rev3t[j]] = make_float2(zr[j], zi[j]);
            }
        }
        WAVE_SYNC();

        // ---- real-split + |X| for k = 8L + j (lane-contiguous), pack f16 ----
        float mg[8];
        #pragma unroll
        for (int j = 0; j < 8; ++j) {
            int k = 8 * L + j;
            if (k == 0) {                    // lane 0, j 0 only
                float2 z0 = Z[0];
                mg[j]     = fabsf(z0.x + z0.y);
                m512v[fi] = fabsf(z0.x - z0.y);
            } else {
                int n2 = 512 - k;
                float2 A  = Z[k  + (k  >> 6)];
                float2 Bv = Z[n2 + (n2 >> 6)];
                float xer = 0.5f * (A.x + Bv.x), xei = 0.5f * (A.y - Bv.y);
                float xo  = 0.5f * (A.y + Bv.y), xoi = -0.5f * (A.x - Bv.x);
                float2 w = R[k];
                float xr = xer + w.x * xo - w.y * xoi;
                float xi = xei + w.x * xoi + w.y * xo;
                mg[j] = sqrtf(xr * xr + xi * xi);
            }
        }
        mgp[fi].x = pk_f16(mg[0], mg[1]);
        mgp[fi].y = pk_f16(mg[2], mg[3]);
        mgp[fi].z = pk_f16(mg[4], mg[5]);
        mgp[fi].w = pk_f16(mg[6], mg[7]);
        WAVE_SYNC();   // all Z reads drained before next frame's writes
    }

    // ---- all FFTs done: overlay mag tile [16][552] f16 onto smem ----
    __syncthreads();
    #pragma unroll
    for (int fi = 0; fi < 4; ++fi) {
        const int row = wv * 4 + fi;
        *(uint4*)(smemc + row * 1104 + 16 * L) = mgp[fi];
        if (L < 20) {   // zero pad bins [512..552), bin 512 = m512
            unsigned v = (L == 0) ? pk_f16(m512v[fi], 0.0f) : 0u;
            *(unsigned*)(smemc + row * 1104 + 1024 + 4 * L) = v;
        }
    }
    __syncthreads();

    // ---- mel projection: D[16 frames][16 mels] per wave, K = 544 ----
    if (wv < 3) {
        const int nl = L & 15, q = L >> 4;
        const char* ap = smemc + nl * 1104 + q * 16;                // A: frame rows
        const _Float16* btp = (const _Float16*)(ws + WS_BT)
                              + (size_t)(wv * 16 + nl) * 544 + q * 8;
        f32x4 acc = {0.0f, 0.0f, 0.0f, 0.0f};
        #pragma unroll
        for (int kk = 0; kk < 17; ++kk) {
            half8 a = *(const half8*)(ap + kk * 64);
            half8 b = *(const half8*)(btp + kk * 32);
            acc = __builtin_amdgcn_mfma_f32_16x16x32_f16(a, b, acc, 0, 0, 0);
        }
        const int mel = wv * 16 + nl;
        if (mel < NMEL) {
            #pragma unroll
            for (int r = 0; r < 4; ++r) {
                int fl = q * 4 + r;                 // C/D: row=(lane>>4)*4+r
                lm[fl * NMEL + mel] = __logf(acc[r] + 1e-6f);
            }
        }
    }
    __syncthreads();

    // ---- DCT + scale + lifter, fp32: 208 threads = 16 frames x 13 ceps ----
    if (tid < 16 * NCEP) {
        const int fl = tid / NCEP, c = tid - fl * NCEP;
        float acc = 0.0f;
        #pragma unroll
        for (int m = 0; m < NMEL; ++m)
            acc += lm[fl * NMEL + m] * ws[WS_DT + m * 13 + c];
        out[(size_t)(blockIdx.x * 16 + fl) * (3 * NCEP) + c] = acc;
    }
}

// ---------------------------------------------------------------------------
// Stage 2: per-batch deltas.
// ---------------------------------------------------------------------------
__global__ __launch_bounds__(128) void mfcc_stage2(float* __restrict__ out)
{
    __shared__ float x [NFRAME * NCEP];
    __shared__ float d1[NFRAME * NCEP];

    const int b = blockIdx.x;
    const int tid = threadIdx.x;
    const int TC = NFRAME * NCEP;

    for (int i = tid; i < TC; i += 128) {
        const int t = i / NCEP, c = i - t * NCEP;
        x[i] = out[((size_t)b * NFRAME + t) * (3 * NCEP) + c];
    }
    __syncthreads();

    for (int i = tid; i < TC; i += 128) {
        const int t = i / NCEP, c = i - t * NCEP;
        float acc = 0.0f;
        #pragma unroll
        for (int k = -2; k <= 2; ++k) {
            if (k == 0) continue;
            int tt = t + k;
            tt = tt < 0 ? 0 : (tt > NFRAME - 1 ? NFRAME - 1 : tt);
            acc += (float)k * x[tt * NCEP + c];
        }
        d1[i] = acc * 0.1f;
    }
    __syncthreads();

    for (int i = tid; i < TC; i += 128) {
        const int t = i / NCEP, c = i - t * NCEP;
        float acc = 0.0f;
        #pragma unroll
        for (int k = -2; k <= 2; ++k) {
            if (k == 0) continue;
            int tt = t + k;
            tt = tt < 0 ? 0 : (tt > NFRAME - 1 ? NFRAME - 1 : tt);
            acc += (float)k * d1[tt * NCEP + c];
        }
        const size_t base = ((size_t)b * NFRAME + t) * (3 * NCEP);
        out[base +     NCEP + c] = d1[i];
        out[base + 2 * NCEP + c] = acc * 0.1f;
    }
}

extern "C" void kernel_launch(void* const* d_in, const int* in_sizes, int n_in,
                              void* d_out, int out_size, void* d_ws, size_t ws_size,
                              hipStream_t stream)
{
    const float* wave   = (const float*)d_in[0];   // [1024][16000] f32
    const float* mel_fb = (const float*)d_in[1];   // [513][40] f32
    float* out = (float*)d_out;                    // [1024][49][39][1] f32
    float* ws  = (float*)d_ws;

    mfcc_prep<<<64, 256, 0, stream>>>(mel_fb, ws);
    mfcc_stage1<<<(BATCH * NFRAME) / 16, 256, 0, stream>>>(wave, ws, out);
    mfcc_stage2<<<BATCH, 128, 0, stream>>>(out);
}